// Round 5
// baseline (206.435 us; speedup 1.0000x reference)
//
#include <hip/hip_runtime.h>
#include <hip/hip_bf16.h>
#include <math.h>

// ---------------------------------------------------------------------------
// TernaryLeNet5 forward.
// R4: fusion round (every dispatch was already < 40us; overhead-dominated).
//   - ternarize: 2 passes, no atomics/memset. Pass1 writes per-block abs-sum
//     partials; pass2 computes delta, writes +-1/0 weights AND masked-sum
//     partials. Alpha is folded into consumer epilogues (alpha>0 commutes
//     with max-pool; applied in f32 -> slightly more accurate).
//   - conv12: conv1 (fp32 VALU) writes its pooled bf16 NHWC tile straight to
//     LDS, conv2 MFMA consumes it in the same kernel (p1h eliminated).
//   - conv3fc: conv3 MFMA (16 img/block, K=50 steps) + fc1 + fc2 + softmax
//     fused; h3 buffer eliminated.
// 4 kernel launches total.
// ---------------------------------------------------------------------------

typedef __attribute__((ext_vector_type(8))) short bf16x8;
typedef __attribute__((ext_vector_type(4))) float f32x4;

// ---- ws layout (float offsets) --------------------------------------------
// pb: pabs[5][16] @0, ps1[5][16] @80, pcnt[5][16] @160
static const size_t OFF_PB    = 0;        // 240 f32
static const size_t OFF_Q1T   = 256;      // [25][32] f32, +-1/0
static const size_t OFF_W2B   = 1056;     // [64][25][32] bf16 = 25600 f32
static const size_t OFF_W3B   = 26656;    // [128][1600] bf16  = 102400 f32
static const size_t OFF_FW1T  = 129056;   // [120][84] f32, +-1/0
static const size_t OFF_FW2T  = 139136;   // [84][10] f32, +-1/0
static const size_t OFF_P2B   = 139976;   // [1024][1600] bf16 = 819200 f32
// total ~3.8 MB

#define BPT 16   // blocks per tensor in ternarize passes

__device__ __forceinline__ ushort f2bf(float v) {   // RNE float->bf16 bits
    unsigned u = __float_as_uint(v);
    unsigned r = (u + 0x7FFFu + ((u >> 16) & 1u)) >> 16;
    return (ushort)r;
}

__device__ __forceinline__ void tensor_select(int tensor,
        const float* w1, const float* w2, const float* w3,
        const float* fw1, const float* fw2,
        const float*& src, int& O, int& K) {
    switch (tensor) {
        case 0: src = w1;  O = 32;  K = 25;   break;
        case 1: src = w2;  O = 64;  K = 800;  break;
        case 2: src = w3;  O = 120; K = 1600; break;
        case 3: src = fw1; O = 84;  K = 120;  break;
        default: src = fw2; O = 10; K = 84;   break;
    }
}

__device__ __forceinline__ float block_sum_256(float v, float* sbuf) {
    #pragma unroll
    for (int off = 32; off > 0; off >>= 1) v += __shfl_down(v, off);
    const int wid = threadIdx.x >> 6;
    if ((threadIdx.x & 63) == 0) sbuf[wid] = v;
    __syncthreads();
    return sbuf[0] + sbuf[1] + sbuf[2] + sbuf[3];
}

// alpha for `tensor` from pass2 partials (all threads compute redundantly)
__device__ __forceinline__ float alpha_of(const float* pb, int tensor) {
    float s1 = 0.f, c = 0.f;
    #pragma unroll
    for (int i = 0; i < BPT; ++i) {
        s1 += pb[80 + tensor * BPT + i];
        c  += pb[160 + tensor * BPT + i];
    }
    return s1 / fmaxf(c, 1.0f);
}

// ---------------------------------------------------------------------------
__global__ __launch_bounds__(256)
void tern_pass1(const float* w1, const float* w2, const float* w3,
                const float* fw1, const float* fw2, float* pb) {
    __shared__ float sbuf[4];
    const int tensor = blockIdx.x / BPT;
    const int blk    = blockIdx.x % BPT;
    const float* src; int O, K;
    tensor_select(tensor, w1, w2, w3, fw1, fw2, src, O, K);
    const int n = O * K;
    float s = 0.f;
    for (int i = blk * 256 + threadIdx.x; i < n; i += BPT * 256)
        s += fabsf(src[i]);
    s = block_sum_256(s, sbuf);
    if (threadIdx.x == 0) pb[tensor * BPT + blk] = s;
}

// pass2: delta from pass1 partials; quantize to +-1/0; write masked partials.
__global__ __launch_bounds__(256)
void tern_pass2(const float* w1, const float* w2, const float* w3,
                const float* fw1, const float* fw2,
                float* q1t, ushort* w2b, ushort* w3b,
                float* fw1t, float* fw2t, float* pb) {
    __shared__ float sbuf[4];
    const int tensor = blockIdx.x / BPT;
    const int blk    = blockIdx.x % BPT;
    const float* src; int O, K;
    tensor_select(tensor, w1, w2, w3, fw1, fw2, src, O, K);
    const int n = O * K;
    float tot = 0.f;
    #pragma unroll
    for (int i = 0; i < BPT; ++i) tot += pb[tensor * BPT + i];
    const float delta = 0.7f * tot / (float)n;

    const ushort BP = 0x3F80u, BN = 0xBF80u;   // bf16 +1, -1
    float s1 = 0.f, cnt = 0.f;

    if (tensor == 2) {
        // w3 -> bf16 [oc][1600] row-linear; zero-fill pad rows 120..127
        for (int i = blk * 256 + threadIdx.x; i < 128 * 1600; i += BPT * 256) {
            ushort qb = 0;
            if (i < n) {
                float w = src[i];
                float aw = fabsf(w);
                if (aw > delta) { s1 += aw; cnt += 1.f; qb = (w > 0.f) ? BP : BN; }
            }
            w3b[i] = qb;
        }
    } else if (tensor == 1) {
        // w2 -> bf16 [oc][tap][ic]; src is [oc][ic][kh][kw]
        for (int i = blk * 256 + threadIdx.x; i < n; i += BPT * 256) {
            float w = src[i];
            float aw = fabsf(w);
            ushort qb = 0;
            if (aw > delta) { s1 += aw; cnt += 1.f; qb = (w > 0.f) ? BP : BN; }
            int oc = i / 800;
            int r  = i - oc * 800;
            int ic = r / 25;
            int tap = r - ic * 25;
            w2b[oc * 800 + tap * 32 + ic] = qb;
        }
    } else {
        float* dst = (tensor == 0) ? q1t : (tensor == 3) ? fw1t : fw2t;
        for (int i = blk * 256 + threadIdx.x; i < n; i += BPT * 256) {
            float w = src[i];
            float aw = fabsf(w);
            float q = 0.f;
            if (aw > delta) { s1 += aw; cnt += 1.f; q = (w > 0.f) ? 1.f : -1.f; }
            int o = i / K;
            int k = i - o * K;
            dst[k * O + o] = q;      // transpose to [k][O]
        }
    }
    s1 = block_sum_256(s1, sbuf);
    __syncthreads();
    cnt = block_sum_256(cnt, sbuf);
    if (threadIdx.x == 0) {
        pb[80 + tensor * BPT + blk]  = s1;
        pb[160 + tensor * BPT + blk] = cnt;
    }
}

// ---------------------------------------------------------------------------
// conv12: per image, conv1 (fp32 VALU, +-1 weights) -> tanh(a1*.+b1) -> pool
// into LDS bf16 NHWC tile, then conv2 MFMA -> pool -> tanh(a2*.+b2) -> p2b.
template<int TBASE, int TCNT>
__device__ __forceinline__ void conv2_phase(
        const ushort* __restrict__ w2b, const ushort* sxt,
        int n0, int mt0, int lane, f32x4 acc[4][2]) {
    const int col = lane & 15, quad = lane >> 4;
    bf16x8 bfr[TCNT][2];
    #pragma unroll
    for (int i = 0; i < TCNT; ++i) {
        const int tap = TBASE + i;
        #pragma unroll
        for (int np = 0; np < 2; ++np) {
            const int oc = n0 + np * 16 + col;
            bfr[i][np] = *(const bf16x8*)(w2b + (oc * 25 + tap) * 32 + quad * 8);
        }
    }
    #pragma unroll
    for (int mi = 0; mi < 4; ++mi) {
        int m = (mt0 + mi) * 16 + col;
        m = m < 100 ? m : 99;                     // clamp padding rows
        const int oh = m / 10, ow = m - oh * 10;
        const ushort* abase = sxt + (oh * 14 + ow) * 40 + quad * 8;
        #pragma unroll
        for (int i = 0; i < TCNT; ++i) {
            const int tap = TBASE + i;
            const int kh = tap / 5, kw = tap - kh * 5;
            bf16x8 af = *(const bf16x8*)(abase + (kh * 14 + kw) * 40);
            acc[mi][0] = __builtin_amdgcn_mfma_f32_16x16x32_bf16(af, bfr[i][0], acc[mi][0], 0, 0, 0);
            acc[mi][1] = __builtin_amdgcn_mfma_f32_16x16x32_bf16(af, bfr[i][1], acc[mi][1], 0, 0, 0);
        }
    }
}

__global__ __launch_bounds__(256)
void conv12_kernel(const float* __restrict__ x, const float* __restrict__ q1t,
                   const float* __restrict__ b1, const ushort* __restrict__ w2b,
                   const float* __restrict__ b2, const float* __restrict__ pb,
                   ushort* __restrict__ p2b) {
    __shared__ __align__(16) ushort sxt[196 * 40];  // pooled1 tile, NHWC, stride 40
    __shared__ float cbuf[64 * 100];                // conv2 out [oc][pix]
    __shared__ float salpha[2];
    // sx (1024 f32) and sw (800 f32) overlay cbuf: dead before cbuf is written
    float* sx = cbuf;
    float* sw = cbuf + 1024;

    const int n = blockIdx.x;
    const int t = threadIdx.x;
    {
        const float4* src = (const float4*)(x + (size_t)n * 1024);
        if (t < 256) ((float4*)sx)[t] = src[t];
        if (t < 200) ((float4*)sw)[t] = ((const float4*)q1t)[t];
        if (t == 0) salpha[0] = alpha_of(pb, 0);
        if (t == 1) salpha[1] = alpha_of(pb, 1);
    }
    __syncthreads();

    // ---- conv1 -> sxt --------------------------------------------------
    const float a1 = salpha[0];
    const int ocg  = t >> 5;
    const int pos0 = t & 31;
    float bias[4];
    #pragma unroll
    for (int o = 0; o < 4; ++o) bias[o] = b1[ocg * 4 + o];

    for (int pos = pos0; pos < 196; pos += 32) {
        const int ph = pos / 14, pw = pos - ph * 14;
        const int r0 = 2 * ph, c0 = 2 * pw;
        float acc[4][4] = {};
        const float4* wp = (const float4*)sw + ocg;
        #pragma unroll
        for (int kh = 0; kh < 5; ++kh) {
            const float* xr = sx + (r0 + kh) * 32 + c0;
            #pragma unroll
            for (int kw = 0; kw < 5; ++kw) {
                const float4 w4 = *wp; wp += 8;
                const float x00 = xr[kw],      x01 = xr[kw + 1];
                const float x10 = xr[kw + 32], x11 = xr[kw + 33];
                acc[0][0] = fmaf(w4.x, x00, acc[0][0]);
                acc[0][1] = fmaf(w4.x, x01, acc[0][1]);
                acc[0][2] = fmaf(w4.x, x10, acc[0][2]);
                acc[0][3] = fmaf(w4.x, x11, acc[0][3]);
                acc[1][0] = fmaf(w4.y, x00, acc[1][0]);
                acc[1][1] = fmaf(w4.y, x01, acc[1][1]);
                acc[1][2] = fmaf(w4.y, x10, acc[1][2]);
                acc[1][3] = fmaf(w4.y, x11, acc[1][3]);
                acc[2][0] = fmaf(w4.z, x00, acc[2][0]);
                acc[2][1] = fmaf(w4.z, x01, acc[2][1]);
                acc[2][2] = fmaf(w4.z, x10, acc[2][2]);
                acc[2][3] = fmaf(w4.z, x11, acc[2][3]);
                acc[3][0] = fmaf(w4.w, x00, acc[3][0]);
                acc[3][1] = fmaf(w4.w, x01, acc[3][1]);
                acc[3][2] = fmaf(w4.w, x10, acc[3][2]);
                acc[3][3] = fmaf(w4.w, x11, acc[3][3]);
            }
        }
        ushort4 qv;
        {
            float m0 = fmaxf(fmaxf(acc[0][0], acc[0][1]), fmaxf(acc[0][2], acc[0][3]));
            float m1 = fmaxf(fmaxf(acc[1][0], acc[1][1]), fmaxf(acc[1][2], acc[1][3]));
            float m2 = fmaxf(fmaxf(acc[2][0], acc[2][1]), fmaxf(acc[2][2], acc[2][3]));
            float m3 = fmaxf(fmaxf(acc[3][0], acc[3][1]), fmaxf(acc[3][2], acc[3][3]));
            qv.x = f2bf(tanhf(fmaf(a1, m0, bias[0])));
            qv.y = f2bf(tanhf(fmaf(a1, m1, bias[1])));
            qv.z = f2bf(tanhf(fmaf(a1, m2, bias[2])));
            qv.w = f2bf(tanhf(fmaf(a1, m3, bias[3])));
        }
        *(ushort4*)(&sxt[pos * 40 + ocg * 4]) = qv;
    }
    __syncthreads();   // conv1 done; sx/sw dead; sxt ready

    // ---- conv2 MFMA ----------------------------------------------------
    const int wave = t >> 6, lane = t & 63;
    const int n0  = (wave & 1) * 32;
    const int mt0 = (wave >> 1) * 4;
    f32x4 acc2[4][2] = {};
    conv2_phase<0, 13>(w2b, sxt, n0, mt0, lane, acc2);
    conv2_phase<13, 12>(w2b, sxt, n0, mt0, lane, acc2);

    {   // C -> cbuf [oc][pix] (overlays sx/sw, safe after the barrier above)
        const int col = lane & 15, quad = lane >> 4;
        #pragma unroll
        for (int mi = 0; mi < 4; ++mi) {
            const int mrow = (mt0 + mi) * 16 + quad * 4;
            if (mrow < 100) {
                #pragma unroll
                for (int np = 0; np < 2; ++np) {
                    const int oc = n0 + np * 16 + col;
                    *(f32x4*)(&cbuf[oc * 100 + mrow]) = acc2[mi][np];
                }
            }
        }
    }
    __syncthreads();

    // pool 2x2 + alpha/bias + tanh -> p2b bf16 [n][1600] (k = oc*25 + pix)
    const float a2 = salpha[1];
    for (int idx = t; idx < 1600; idx += 256) {
        const int oc = idx / 25, r = idx - oc * 25;
        const int ph = r / 5, pw = r - ph * 5;
        const float* c0 = &cbuf[oc * 100 + ph * 20 + pw * 2];
        float m = fmaxf(fmaxf(c0[0], c0[1]), fmaxf(c0[10], c0[11]));
        p2b[(size_t)n * 1600 + idx] = f2bf(tanhf(fmaf(a2, m, b2[oc])));
    }
}

// ---------------------------------------------------------------------------
// conv3fc: block = 16 images. conv3 MFMA (4 waves x 2 oc-tiles x K=50 steps)
// -> h3 tile in LDS -> fc1 -> fc2 -> softmax -> out.
__global__ __launch_bounds__(256)
void conv3fc_kernel(const ushort* __restrict__ p2b, const ushort* __restrict__ w3b,
                    const float* __restrict__ b3, const float* __restrict__ fw1t,
                    const float* __restrict__ fb1, const float* __restrict__ fw2t,
                    const float* __restrict__ fb2, const float* __restrict__ pb,
                    float* __restrict__ out) {
    __shared__ float sh3[16][120];
    __shared__ float sh4[16][84];
    __shared__ float slog[16][10];
    __shared__ float salpha[3];
    const int t = threadIdx.x;
    const int wave = t >> 6, lane = t & 63;
    const int col = lane & 15, quad = lane >> 4;
    const int mt = blockIdx.x;                 // images mt*16 .. +15

    if (t < 3) salpha[t] = alpha_of(pb, t + 2);

    const ushort* Abase = p2b + (size_t)(mt * 16 + col) * 1600 + quad * 8;
    const ushort* B0 = w3b + (size_t)(wave * 32 + col) * 1600 + quad * 8;
    const ushort* B1 = B0 + 16 * 1600;

    f32x4 acc0 = {}, acc1 = {};
    #pragma unroll 5
    for (int s = 0; s < 50; ++s) {
        bf16x8 af = *(const bf16x8*)(Abase + s * 32);
        bf16x8 b0 = *(const bf16x8*)(B0 + s * 32);
        bf16x8 b1 = *(const bf16x8*)(B1 + s * 32);
        acc0 = __builtin_amdgcn_mfma_f32_16x16x32_bf16(af, b0, acc0, 0, 0, 0);
        acc1 = __builtin_amdgcn_mfma_f32_16x16x32_bf16(af, b1, acc1, 0, 0, 0);
    }
    __syncthreads();   // salpha visible

    const float a3 = salpha[0];
    {   // h3 tile: img_local = quad*4+r, oc = wave*32 + {col, 16+col}
        #pragma unroll
        for (int r = 0; r < 4; ++r) {
            const int img = quad * 4 + r;
            const int oc0 = wave * 32 + col;       // <= 111, always valid
            sh3[img][oc0] = tanhf(fmaf(a3, acc0[r], b3[oc0]));
            const int oc1 = oc0 + 16;
            if (oc1 < 120) sh3[img][oc1] = tanhf(fmaf(a3, acc1[r], b3[oc1]));
        }
    }
    __syncthreads();

    // fc1: 16*84 outputs
    const float af1 = salpha[1];
    for (int idx = t; idx < 16 * 84; idx += 256) {
        const int img = idx / 84, oc = idx - img * 84;
        float s = 0.f;
        #pragma unroll 4
        for (int k = 0; k < 120; ++k) s = fmaf(fw1t[k * 84 + oc], sh3[img][k], s);
        sh4[img][oc] = tanhf(fmaf(af1, s, fb1[oc]));
    }
    __syncthreads();

    // fc2 + logits
    const float af2 = salpha[2];
    for (int idx = t; idx < 160; idx += 256) {
        const int img = idx / 10, oc = idx - img * 10;
        float s = 0.f;
        #pragma unroll 4
        for (int k = 0; k < 84; ++k) s = fmaf(fw2t[k * 10 + oc], sh4[img][k], s);
        const float lg = fmaf(af2, s, fb2[oc]);
        slog[img][oc] = lg;
        out[(size_t)(mt * 16 + img) * 10 + oc] = lg;
    }
    __syncthreads();

    // softmax
    for (int idx = t; idx < 160; idx += 256) {
        const int img = idx / 10, oc = idx - img * 10;
        float m = -INFINITY;
        #pragma unroll
        for (int i = 0; i < 10; ++i) m = fmaxf(m, slog[img][i]);
        float ssum = 0.f;
        #pragma unroll
        for (int i = 0; i < 10; ++i) ssum += expf(slog[img][i] - m);
        out[10240 + (size_t)(mt * 16 + img) * 10 + oc] = expf(slog[img][oc] - m) / ssum;
    }
}

// ---------------------------------------------------------------------------
extern "C" void kernel_launch(void* const* d_in, const int* in_sizes, int n_in,
                              void* d_out, int out_size, void* d_ws, size_t ws_size,
                              hipStream_t stream) {
    const float* x   = (const float*)d_in[0];
    const float* w1  = (const float*)d_in[1];
    const float* b1  = (const float*)d_in[2];
    const float* w2  = (const float*)d_in[3];
    const float* b2  = (const float*)d_in[4];
    const float* w3  = (const float*)d_in[5];
    const float* b3  = (const float*)d_in[6];
    const float* fw1 = (const float*)d_in[7];
    const float* fb1 = (const float*)d_in[8];
    const float* fw2 = (const float*)d_in[9];
    const float* fb2 = (const float*)d_in[10];

    float* ws = (float*)d_ws;
    float*  pb   = ws + OFF_PB;
    float*  q1t  = ws + OFF_Q1T;
    ushort* w2b  = (ushort*)(ws + OFF_W2B);
    ushort* w3b  = (ushort*)(ws + OFF_W3B);
    float*  fw1t = ws + OFF_FW1T;
    float*  fw2t = ws + OFF_FW2T;
    ushort* p2b  = (ushort*)(ws + OFF_P2B);
    float*  out  = (float*)d_out;

    tern_pass1<<<5 * BPT, 256, 0, stream>>>(w1, w2, w3, fw1, fw2, pb);
    tern_pass2<<<5 * BPT, 256, 0, stream>>>(w1, w2, w3, fw1, fw2,
                                            q1t, w2b, w3b, fw1t, fw2t, pb);
    conv12_kernel<<<1024, 256, 0, stream>>>(x, q1t, b1, w2b, b2, pb, p2b);
    conv3fc_kernel<<<64, 256, 0, stream>>>(p2b, w3b, b3, fw1t, fb1, fw2t, fb2, pb, out);
}

// Round 6
// 166.127 us; speedup vs baseline: 1.2426x; 1.2426x over previous
//
#include <hip/hip_runtime.h>
#include <hip/hip_bf16.h>
#include <math.h>

// ---------------------------------------------------------------------------
// TernaryLeNet5 forward.
// R5: UN-fuse conv3fc. R4's fused version ran at 64 blocks -> 2.7% occupancy,
// 63.5us (latency-bound; 1 wave per 4 SIMDs). Back to the R3 structure:
//   conv3_mfma: 256 blocks (64 m-tiles x 4 oc-pairs), 4 waves split K,
//               LDS reduce, tanh(a3*s+b3) -> h3.
//   fc_kernel:  1024 blocks x 128 thr, alpha folded.
// Kept from R4: 2-pass ternarize (partials, no atomics/memset), conv12
// fusion (1024 blocks — parallelism preserved), +-1 weights with alpha
// applied in f32 epilogues.
// Fusion rule learned: only fuse if the grid stays >= ~256 blocks.
// ---------------------------------------------------------------------------

typedef __attribute__((ext_vector_type(8))) short bf16x8;
typedef __attribute__((ext_vector_type(4))) float f32x4;

// ---- ws layout (float offsets) --------------------------------------------
// pb: pabs[5][16] @0, ps1[5][16] @80, pcnt[5][16] @160
static const size_t OFF_PB    = 0;        // 240 f32
static const size_t OFF_Q1T   = 256;      // [25][32] f32, +-1/0
static const size_t OFF_W2B   = 1056;     // [64][25][32] bf16 = 25600 f32
static const size_t OFF_W3B   = 26656;    // [128][1600] bf16  = 102400 f32
static const size_t OFF_FW1T  = 129056;   // [120][84] f32, +-1/0
static const size_t OFF_FW2T  = 139136;   // [84][10] f32, +-1/0
static const size_t OFF_P2B   = 139976;   // [1024][1600] bf16 = 819200 f32
static const size_t OFF_H3    = 959176;   // [1024][120] f32
// total ~4.3 MB

#define BPT 16   // blocks per tensor in ternarize passes

__device__ __forceinline__ ushort f2bf(float v) {   // RNE float->bf16 bits
    unsigned u = __float_as_uint(v);
    unsigned r = (u + 0x7FFFu + ((u >> 16) & 1u)) >> 16;
    return (ushort)r;
}

__device__ __forceinline__ void tensor_select(int tensor,
        const float* w1, const float* w2, const float* w3,
        const float* fw1, const float* fw2,
        const float*& src, int& O, int& K) {
    switch (tensor) {
        case 0: src = w1;  O = 32;  K = 25;   break;
        case 1: src = w2;  O = 64;  K = 800;  break;
        case 2: src = w3;  O = 120; K = 1600; break;
        case 3: src = fw1; O = 84;  K = 120;  break;
        default: src = fw2; O = 10; K = 84;   break;
    }
}

__device__ __forceinline__ float block_sum_256(float v, float* sbuf) {
    #pragma unroll
    for (int off = 32; off > 0; off >>= 1) v += __shfl_down(v, off);
    const int wid = threadIdx.x >> 6;
    if ((threadIdx.x & 63) == 0) sbuf[wid] = v;
    __syncthreads();
    return sbuf[0] + sbuf[1] + sbuf[2] + sbuf[3];
}

// alpha for `tensor` from pass2 partials (redundant per-thread compute)
__device__ __forceinline__ float alpha_of(const float* pb, int tensor) {
    float s1 = 0.f, c = 0.f;
    #pragma unroll
    for (int i = 0; i < BPT; ++i) {
        s1 += pb[80 + tensor * BPT + i];
        c  += pb[160 + tensor * BPT + i];
    }
    return s1 / fmaxf(c, 1.0f);
}

// ---------------------------------------------------------------------------
__global__ __launch_bounds__(256)
void tern_pass1(const float* w1, const float* w2, const float* w3,
                const float* fw1, const float* fw2, float* pb) {
    __shared__ float sbuf[4];
    const int tensor = blockIdx.x / BPT;
    const int blk    = blockIdx.x % BPT;
    const float* src; int O, K;
    tensor_select(tensor, w1, w2, w3, fw1, fw2, src, O, K);
    const int n = O * K;
    float s = 0.f;
    for (int i = blk * 256 + threadIdx.x; i < n; i += BPT * 256)
        s += fabsf(src[i]);
    s = block_sum_256(s, sbuf);
    if (threadIdx.x == 0) pb[tensor * BPT + blk] = s;
}

// pass2: delta from pass1 partials; quantize to +-1/0; write masked partials.
__global__ __launch_bounds__(256)
void tern_pass2(const float* w1, const float* w2, const float* w3,
                const float* fw1, const float* fw2,
                float* q1t, ushort* w2b, ushort* w3b,
                float* fw1t, float* fw2t, float* pb) {
    __shared__ float sbuf[4];
    const int tensor = blockIdx.x / BPT;
    const int blk    = blockIdx.x % BPT;
    const float* src; int O, K;
    tensor_select(tensor, w1, w2, w3, fw1, fw2, src, O, K);
    const int n = O * K;
    float tot = 0.f;
    #pragma unroll
    for (int i = 0; i < BPT; ++i) tot += pb[tensor * BPT + i];
    const float delta = 0.7f * tot / (float)n;

    const ushort BP = 0x3F80u, BN = 0xBF80u;   // bf16 +1, -1
    float s1 = 0.f, cnt = 0.f;

    if (tensor == 2) {
        // w3 -> bf16 [oc][1600] row-linear; zero-fill pad rows 120..127
        for (int i = blk * 256 + threadIdx.x; i < 128 * 1600; i += BPT * 256) {
            ushort qb = 0;
            if (i < n) {
                float w = src[i];
                float aw = fabsf(w);
                if (aw > delta) { s1 += aw; cnt += 1.f; qb = (w > 0.f) ? BP : BN; }
            }
            w3b[i] = qb;
        }
    } else if (tensor == 1) {
        // w2 -> bf16 [oc][tap][ic]; src is [oc][ic][kh][kw]
        for (int i = blk * 256 + threadIdx.x; i < n; i += BPT * 256) {
            float w = src[i];
            float aw = fabsf(w);
            ushort qb = 0;
            if (aw > delta) { s1 += aw; cnt += 1.f; qb = (w > 0.f) ? BP : BN; }
            int oc = i / 800;
            int r  = i - oc * 800;
            int ic = r / 25;
            int tap = r - ic * 25;
            w2b[oc * 800 + tap * 32 + ic] = qb;
        }
    } else {
        float* dst = (tensor == 0) ? q1t : (tensor == 3) ? fw1t : fw2t;
        for (int i = blk * 256 + threadIdx.x; i < n; i += BPT * 256) {
            float w = src[i];
            float aw = fabsf(w);
            float q = 0.f;
            if (aw > delta) { s1 += aw; cnt += 1.f; q = (w > 0.f) ? 1.f : -1.f; }
            int o = i / K;
            int k = i - o * K;
            dst[k * O + o] = q;      // transpose to [k][O]
        }
    }
    s1 = block_sum_256(s1, sbuf);
    __syncthreads();
    cnt = block_sum_256(cnt, sbuf);
    if (threadIdx.x == 0) {
        pb[80 + tensor * BPT + blk]  = s1;
        pb[160 + tensor * BPT + blk] = cnt;
    }
}

// ---------------------------------------------------------------------------
// conv12: per image, conv1 (fp32 VALU, +-1 weights) -> tanh(a1*.+b1) -> pool
// into LDS bf16 NHWC tile, then conv2 MFMA -> pool -> tanh(a2*.+b2) -> p2b.
template<int TBASE, int TCNT>
__device__ __forceinline__ void conv2_phase(
        const ushort* __restrict__ w2b, const ushort* sxt,
        int n0, int mt0, int lane, f32x4 acc[4][2]) {
    const int col = lane & 15, quad = lane >> 4;
    bf16x8 bfr[TCNT][2];
    #pragma unroll
    for (int i = 0; i < TCNT; ++i) {
        const int tap = TBASE + i;
        #pragma unroll
        for (int np = 0; np < 2; ++np) {
            const int oc = n0 + np * 16 + col;
            bfr[i][np] = *(const bf16x8*)(w2b + (oc * 25 + tap) * 32 + quad * 8);
        }
    }
    #pragma unroll
    for (int mi = 0; mi < 4; ++mi) {
        int m = (mt0 + mi) * 16 + col;
        m = m < 100 ? m : 99;                     // clamp padding rows
        const int oh = m / 10, ow = m - oh * 10;
        const ushort* abase = sxt + (oh * 14 + ow) * 40 + quad * 8;
        #pragma unroll
        for (int i = 0; i < TCNT; ++i) {
            const int tap = TBASE + i;
            const int kh = tap / 5, kw = tap - kh * 5;
            bf16x8 af = *(const bf16x8*)(abase + (kh * 14 + kw) * 40);
            acc[mi][0] = __builtin_amdgcn_mfma_f32_16x16x32_bf16(af, bfr[i][0], acc[mi][0], 0, 0, 0);
            acc[mi][1] = __builtin_amdgcn_mfma_f32_16x16x32_bf16(af, bfr[i][1], acc[mi][1], 0, 0, 0);
        }
    }
}

__global__ __launch_bounds__(256)
void conv12_kernel(const float* __restrict__ x, const float* __restrict__ q1t,
                   const float* __restrict__ b1, const ushort* __restrict__ w2b,
                   const float* __restrict__ b2, const float* __restrict__ pb,
                   ushort* __restrict__ p2b) {
    __shared__ __align__(16) ushort sxt[196 * 40];  // pooled1 tile, NHWC, stride 40
    __shared__ float cbuf[64 * 100];                // conv2 out [oc][pix]
    __shared__ float salpha[2];
    // sx (1024 f32) and sw (800 f32) overlay cbuf: dead before cbuf is written
    float* sx = cbuf;
    float* sw = cbuf + 1024;

    const int n = blockIdx.x;
    const int t = threadIdx.x;
    {
        const float4* src = (const float4*)(x + (size_t)n * 1024);
        if (t < 256) ((float4*)sx)[t] = src[t];
        if (t < 200) ((float4*)sw)[t] = ((const float4*)q1t)[t];
        if (t == 0) salpha[0] = alpha_of(pb, 0);
        if (t == 1) salpha[1] = alpha_of(pb, 1);
    }
    __syncthreads();

    // ---- conv1 -> sxt --------------------------------------------------
    const float a1 = salpha[0];
    const int ocg  = t >> 5;
    const int pos0 = t & 31;
    float bias[4];
    #pragma unroll
    for (int o = 0; o < 4; ++o) bias[o] = b1[ocg * 4 + o];

    for (int pos = pos0; pos < 196; pos += 32) {
        const int ph = pos / 14, pw = pos - ph * 14;
        const int r0 = 2 * ph, c0 = 2 * pw;
        float acc[4][4] = {};
        const float4* wp = (const float4*)sw + ocg;
        #pragma unroll
        for (int kh = 0; kh < 5; ++kh) {
            const float* xr = sx + (r0 + kh) * 32 + c0;
            #pragma unroll
            for (int kw = 0; kw < 5; ++kw) {
                const float4 w4 = *wp; wp += 8;
                const float x00 = xr[kw],      x01 = xr[kw + 1];
                const float x10 = xr[kw + 32], x11 = xr[kw + 33];
                acc[0][0] = fmaf(w4.x, x00, acc[0][0]);
                acc[0][1] = fmaf(w4.x, x01, acc[0][1]);
                acc[0][2] = fmaf(w4.x, x10, acc[0][2]);
                acc[0][3] = fmaf(w4.x, x11, acc[0][3]);
                acc[1][0] = fmaf(w4.y, x00, acc[1][0]);
                acc[1][1] = fmaf(w4.y, x01, acc[1][1]);
                acc[1][2] = fmaf(w4.y, x10, acc[1][2]);
                acc[1][3] = fmaf(w4.y, x11, acc[1][3]);
                acc[2][0] = fmaf(w4.z, x00, acc[2][0]);
                acc[2][1] = fmaf(w4.z, x01, acc[2][1]);
                acc[2][2] = fmaf(w4.z, x10, acc[2][2]);
                acc[2][3] = fmaf(w4.z, x11, acc[2][3]);
                acc[3][0] = fmaf(w4.w, x00, acc[3][0]);
                acc[3][1] = fmaf(w4.w, x01, acc[3][1]);
                acc[3][2] = fmaf(w4.w, x10, acc[3][2]);
                acc[3][3] = fmaf(w4.w, x11, acc[3][3]);
            }
        }
        ushort4 qv;
        {
            float m0 = fmaxf(fmaxf(acc[0][0], acc[0][1]), fmaxf(acc[0][2], acc[0][3]));
            float m1 = fmaxf(fmaxf(acc[1][0], acc[1][1]), fmaxf(acc[1][2], acc[1][3]));
            float m2 = fmaxf(fmaxf(acc[2][0], acc[2][1]), fmaxf(acc[2][2], acc[2][3]));
            float m3 = fmaxf(fmaxf(acc[3][0], acc[3][1]), fmaxf(acc[3][2], acc[3][3]));
            qv.x = f2bf(tanhf(fmaf(a1, m0, bias[0])));
            qv.y = f2bf(tanhf(fmaf(a1, m1, bias[1])));
            qv.z = f2bf(tanhf(fmaf(a1, m2, bias[2])));
            qv.w = f2bf(tanhf(fmaf(a1, m3, bias[3])));
        }
        *(ushort4*)(&sxt[pos * 40 + ocg * 4]) = qv;
    }
    __syncthreads();   // conv1 done; sx/sw dead; sxt ready

    // ---- conv2 MFMA ----------------------------------------------------
    const int wave = t >> 6, lane = t & 63;
    const int n0  = (wave & 1) * 32;
    const int mt0 = (wave >> 1) * 4;
    f32x4 acc2[4][2] = {};
    conv2_phase<0, 13>(w2b, sxt, n0, mt0, lane, acc2);
    conv2_phase<13, 12>(w2b, sxt, n0, mt0, lane, acc2);

    {   // C -> cbuf [oc][pix] (overlays sx/sw, safe after the barrier above)
        const int col = lane & 15, quad = lane >> 4;
        #pragma unroll
        for (int mi = 0; mi < 4; ++mi) {
            const int mrow = (mt0 + mi) * 16 + quad * 4;
            if (mrow < 100) {
                #pragma unroll
                for (int np = 0; np < 2; ++np) {
                    const int oc = n0 + np * 16 + col;
                    *(f32x4*)(&cbuf[oc * 100 + mrow]) = acc2[mi][np];
                }
            }
        }
    }
    __syncthreads();

    // pool 2x2 + alpha/bias + tanh -> p2b bf16 [n][1600] (k = oc*25 + pix)
    const float a2 = salpha[1];
    for (int idx = t; idx < 1600; idx += 256) {
        const int oc = idx / 25, r = idx - oc * 25;
        const int ph = r / 5, pw = r - ph * 5;
        const float* c0 = &cbuf[oc * 100 + ph * 20 + pw * 2];
        float m = fmaxf(fmaxf(c0[0], c0[1]), fmaxf(c0[10], c0[11]));
        p2b[(size_t)n * 1600 + idx] = f2bf(tanhf(fmaf(a2, m, b2[oc])));
    }
}

// ---------------------------------------------------------------------------
// conv3 as MFMA GEMM: h3[1024][120] = tanh(a3*(P2 x W3^T) + b3)
// Grid 256 = 64 m-tiles x 4 oc-pairs. Waves split K 13/13/12/12; LDS reduce.
template<int STEPS>
__device__ __forceinline__ void conv3_chunk(const ushort* Abase, const ushort* B0,
                                            const ushort* B1, f32x4& acc0, f32x4& acc1) {
    #pragma unroll
    for (int s = 0; s < STEPS; ++s) {
        bf16x8 af = *(const bf16x8*)(Abase + s * 32);
        bf16x8 b0 = *(const bf16x8*)(B0 + s * 32);
        bf16x8 b1 = *(const bf16x8*)(B1 + s * 32);
        acc0 = __builtin_amdgcn_mfma_f32_16x16x32_bf16(af, b0, acc0, 0, 0, 0);
        acc1 = __builtin_amdgcn_mfma_f32_16x16x32_bf16(af, b1, acc1, 0, 0, 0);
    }
}

__global__ __launch_bounds__(256)
void conv3_mfma(const ushort* __restrict__ p2b, const ushort* __restrict__ w3b,
                const float* __restrict__ b3, const float* __restrict__ pb,
                float* __restrict__ h3) {
    __shared__ float red[4][64][8];   // [wave][lane][np*4+reg]
    __shared__ float salpha;
    const int t = threadIdx.x;
    const int wave = t >> 6, lane = t & 63;
    const int mt = blockIdx.x >> 2;       // 0..63
    const int npair = blockIdx.x & 3;     // 0..3
    const int col = lane & 15, quad = lane >> 4;
    const int kstart = (wave < 2) ? wave * 13 : 26 + (wave - 2) * 12;  // 0,13,26,38

    if (t == 0) salpha = alpha_of(pb, 2);

    const ushort* Abase = p2b + (size_t)(mt * 16 + col) * 1600 + kstart * 32 + quad * 8;
    const ushort* B0 = w3b + (size_t)(npair * 32 + col) * 1600 + kstart * 32 + quad * 8;
    const ushort* B1 = B0 + 16 * 1600;

    f32x4 acc0 = {}, acc1 = {};
    if (wave < 2) conv3_chunk<13>(Abase, B0, B1, acc0, acc1);
    else          conv3_chunk<12>(Abase, B0, B1, acc0, acc1);

    #pragma unroll
    for (int r = 0; r < 4; ++r) {
        red[wave][lane][r]     = acc0[r];
        red[wave][lane][4 + r] = acc1[r];
    }
    __syncthreads();

    {   // thread t: lane l = t&63, reg vh = t>>6; handles np = 0 and 1
        const float a3 = salpha;
        const int l = t & 63, vh = t >> 6;
        const int lcol = l & 15, lquad = l >> 4;
        const int img = mt * 16 + lquad * 4 + vh;
        #pragma unroll
        for (int j = 0; j < 2; ++j) {
            const int v = j * 4 + vh;
            float s = red[0][l][v] + red[1][l][v] + red[2][l][v] + red[3][l][v];
            const int oc = npair * 32 + j * 16 + lcol;
            if (oc < 120) h3[(size_t)img * 120 + oc] = tanhf(fmaf(a3, s, b3[oc]));
        }
    }
}

// ---------------------------------------------------------------------------
// fc1 + tanh + fc2 + softmax. Block per image; alpha folded.
__global__ __launch_bounds__(128)
void fc_kernel(const float* __restrict__ h3, const float* __restrict__ fw1t,
               const float* __restrict__ fb1, const float* __restrict__ fw2t,
               const float* __restrict__ fb2, const float* __restrict__ pb,
               float* __restrict__ out) {
    const int n = blockIdx.x;
    __shared__ float sh[120];
    __shared__ float sh4[84];
    __shared__ float sl[10];
    __shared__ float salpha[2];
    const int t = threadIdx.x;
    if (t < 120) sh[t] = h3[(size_t)n * 120 + t];
    if (t == 120) salpha[0] = alpha_of(pb, 3);
    if (t == 121) salpha[1] = alpha_of(pb, 4);
    __syncthreads();
    if (t < 84) {
        const float af1 = salpha[0];
        float a = 0.f;
        #pragma unroll 4
        for (int k = 0; k < 120; ++k) a = fmaf(fw1t[k * 84 + t], sh[k], a);
        sh4[t] = tanhf(fmaf(af1, a, fb1[t]));
    }
    __syncthreads();
    if (t < 10) {
        const float af2 = salpha[1];
        float a = 0.f;
        #pragma unroll 4
        for (int k = 0; k < 84; ++k) a = fmaf(fw2t[k * 10 + t], sh4[k], a);
        const float lg = fmaf(af2, a, fb2[t]);
        sl[t] = lg;
        out[(size_t)n * 10 + t] = lg;
    }
    __syncthreads();
    if (t < 10) {
        float m = -INFINITY;
        #pragma unroll
        for (int i = 0; i < 10; ++i) m = fmaxf(m, sl[i]);
        float s = 0.f;
        #pragma unroll
        for (int i = 0; i < 10; ++i) s += expf(sl[i] - m);
        out[10240 + (size_t)n * 10 + t] = expf(sl[t] - m) / s;
    }
}

// ---------------------------------------------------------------------------
extern "C" void kernel_launch(void* const* d_in, const int* in_sizes, int n_in,
                              void* d_out, int out_size, void* d_ws, size_t ws_size,
                              hipStream_t stream) {
    const float* x   = (const float*)d_in[0];
    const float* w1  = (const float*)d_in[1];
    const float* b1  = (const float*)d_in[2];
    const float* w2  = (const float*)d_in[3];
    const float* b2  = (const float*)d_in[4];
    const float* w3  = (const float*)d_in[5];
    const float* b3  = (const float*)d_in[6];
    const float* fw1 = (const float*)d_in[7];
    const float* fb1 = (const float*)d_in[8];
    const float* fw2 = (const float*)d_in[9];
    const float* fb2 = (const float*)d_in[10];

    float* ws = (float*)d_ws;
    float*  pb   = ws + OFF_PB;
    float*  q1t  = ws + OFF_Q1T;
    ushort* w2b  = (ushort*)(ws + OFF_W2B);
    ushort* w3b  = (ushort*)(ws + OFF_W3B);
    float*  fw1t = ws + OFF_FW1T;
    float*  fw2t = ws + OFF_FW2T;
    ushort* p2b  = (ushort*)(ws + OFF_P2B);
    float*  h3   = ws + OFF_H3;
    float*  out  = (float*)d_out;

    tern_pass1<<<5 * BPT, 256, 0, stream>>>(w1, w2, w3, fw1, fw2, pb);
    tern_pass2<<<5 * BPT, 256, 0, stream>>>(w1, w2, w3, fw1, fw2,
                                            q1t, w2b, w3b, fw1t, fw2t, pb);
    conv12_kernel<<<1024, 256, 0, stream>>>(x, q1t, b1, w2b, b2, pb, p2b);
    conv3_mfma<<<256, 256, 0, stream>>>(p2b, w3b, b3, pb, h3);
    fc_kernel<<<1024, 128, 0, stream>>>(h3, fw1t, fb1, fw2t, fb2, pb, out);
}

// Round 7
// 163.157 us; speedup vs baseline: 1.2653x; 1.0182x over previous
//
#include <hip/hip_runtime.h>
#include <hip/hip_bf16.h>
#include <math.h>

// ---------------------------------------------------------------------------
// TernaryLeNet5 forward.
// R6: conv12 was top dispatch (50us, VALUBusy 57%, Occ 18%, LDS 41.5KB).
//   - conv1 inner: x values register-tiled via 6x float2 LDS loads per
//     (pos,kh); kw loop runs from registers (125 -> ~55 LDS instr/pos).
//   - conv2 epilogue: horizontal pool in-register from C fragment (lane owns
//     4 consecutive pixels; width 10 even -> (2k,2k+1) always h-pairs);
//     LDS half-pooled hbuf[64][50] f32 (12.8KB) replaces cbuf[64][100]
//     (25.6KB). LDS 41.5 -> ~28.5KB -> 5 blocks/CU, full grid co-resident.
//   - tanh_fast (exp-based, ~8 VALU, err ~1e-6) everywhere.
// Fusion rule from R4: only fuse if grid stays >= ~256 blocks.
// ---------------------------------------------------------------------------

typedef __attribute__((ext_vector_type(8))) short bf16x8;
typedef __attribute__((ext_vector_type(4))) float f32x4;

// ---- ws layout (float offsets) --------------------------------------------
// pb: pabs[5][16] @0, ps1[5][16] @80, pcnt[5][16] @160
static const size_t OFF_PB    = 0;        // 240 f32
static const size_t OFF_Q1T   = 256;      // [25][32] f32, +-1/0
static const size_t OFF_W2B   = 1056;     // [64][25][32] bf16 = 25600 f32
static const size_t OFF_W3B   = 26656;    // [128][1600] bf16  = 102400 f32
static const size_t OFF_FW1T  = 129056;   // [120][84] f32, +-1/0
static const size_t OFF_FW2T  = 139136;   // [84][10] f32, +-1/0
static const size_t OFF_P2B   = 139976;   // [1024][1600] bf16 = 819200 f32
static const size_t OFF_H3    = 959176;   // [1024][120] f32
// total ~4.3 MB

#define BPT 16   // blocks per tensor in ternarize passes

__device__ __forceinline__ ushort f2bf(float v) {   // RNE float->bf16 bits
    unsigned u = __float_as_uint(v);
    unsigned r = (u + 0x7FFFu + ((u >> 16) & 1u)) >> 16;
    return (ushort)r;
}

// tanh via hw exp: 1 - 2e/(1+e), e = exp(-2|x|) in (0,1] -> no overflow.
// ~8 VALU vs ~20+ for tanhf; abs err ~1e-6.
__device__ __forceinline__ float tanh_fast(float x) {
    float e = __expf(-2.0f * fabsf(x));
    float r = 1.0f - 2.0f * e / (1.0f + e);
    return copysignf(r, x);
}

__device__ __forceinline__ void tensor_select(int tensor,
        const float* w1, const float* w2, const float* w3,
        const float* fw1, const float* fw2,
        const float*& src, int& O, int& K) {
    switch (tensor) {
        case 0: src = w1;  O = 32;  K = 25;   break;
        case 1: src = w2;  O = 64;  K = 800;  break;
        case 2: src = w3;  O = 120; K = 1600; break;
        case 3: src = fw1; O = 84;  K = 120;  break;
        default: src = fw2; O = 10; K = 84;   break;
    }
}

__device__ __forceinline__ float block_sum_256(float v, float* sbuf) {
    #pragma unroll
    for (int off = 32; off > 0; off >>= 1) v += __shfl_down(v, off);
    const int wid = threadIdx.x >> 6;
    if ((threadIdx.x & 63) == 0) sbuf[wid] = v;
    __syncthreads();
    return sbuf[0] + sbuf[1] + sbuf[2] + sbuf[3];
}

// alpha for `tensor` from pass2 partials (redundant per-thread compute)
__device__ __forceinline__ float alpha_of(const float* pb, int tensor) {
    float s1 = 0.f, c = 0.f;
    #pragma unroll
    for (int i = 0; i < BPT; ++i) {
        s1 += pb[80 + tensor * BPT + i];
        c  += pb[160 + tensor * BPT + i];
    }
    return s1 / fmaxf(c, 1.0f);
}

// ---------------------------------------------------------------------------
__global__ __launch_bounds__(256)
void tern_pass1(const float* w1, const float* w2, const float* w3,
                const float* fw1, const float* fw2, float* pb) {
    __shared__ float sbuf[4];
    const int tensor = blockIdx.x / BPT;
    const int blk    = blockIdx.x % BPT;
    const float* src; int O, K;
    tensor_select(tensor, w1, w2, w3, fw1, fw2, src, O, K);
    const int n = O * K;
    float s = 0.f;
    for (int i = blk * 256 + threadIdx.x; i < n; i += BPT * 256)
        s += fabsf(src[i]);
    s = block_sum_256(s, sbuf);
    if (threadIdx.x == 0) pb[tensor * BPT + blk] = s;
}

// pass2: delta from pass1 partials; quantize to +-1/0; write masked partials.
__global__ __launch_bounds__(256)
void tern_pass2(const float* w1, const float* w2, const float* w3,
                const float* fw1, const float* fw2,
                float* q1t, ushort* w2b, ushort* w3b,
                float* fw1t, float* fw2t, float* pb) {
    __shared__ float sbuf[4];
    const int tensor = blockIdx.x / BPT;
    const int blk    = blockIdx.x % BPT;
    const float* src; int O, K;
    tensor_select(tensor, w1, w2, w3, fw1, fw2, src, O, K);
    const int n = O * K;
    float tot = 0.f;
    #pragma unroll
    for (int i = 0; i < BPT; ++i) tot += pb[tensor * BPT + i];
    const float delta = 0.7f * tot / (float)n;

    const ushort BP = 0x3F80u, BN = 0xBF80u;   // bf16 +1, -1
    float s1 = 0.f, cnt = 0.f;

    if (tensor == 2) {
        // w3 -> bf16 [oc][1600] row-linear; zero-fill pad rows 120..127
        for (int i = blk * 256 + threadIdx.x; i < 128 * 1600; i += BPT * 256) {
            ushort qb = 0;
            if (i < n) {
                float w = src[i];
                float aw = fabsf(w);
                if (aw > delta) { s1 += aw; cnt += 1.f; qb = (w > 0.f) ? BP : BN; }
            }
            w3b[i] = qb;
        }
    } else if (tensor == 1) {
        // w2 -> bf16 [oc][tap][ic]; src is [oc][ic][kh][kw]
        for (int i = blk * 256 + threadIdx.x; i < n; i += BPT * 256) {
            float w = src[i];
            float aw = fabsf(w);
            ushort qb = 0;
            if (aw > delta) { s1 += aw; cnt += 1.f; qb = (w > 0.f) ? BP : BN; }
            int oc = i / 800;
            int r  = i - oc * 800;
            int ic = r / 25;
            int tap = r - ic * 25;
            w2b[oc * 800 + tap * 32 + ic] = qb;
        }
    } else {
        float* dst = (tensor == 0) ? q1t : (tensor == 3) ? fw1t : fw2t;
        for (int i = blk * 256 + threadIdx.x; i < n; i += BPT * 256) {
            float w = src[i];
            float aw = fabsf(w);
            float q = 0.f;
            if (aw > delta) { s1 += aw; cnt += 1.f; q = (w > 0.f) ? 1.f : -1.f; }
            int o = i / K;
            int k = i - o * K;
            dst[k * O + o] = q;      // transpose to [k][O]
        }
    }
    s1 = block_sum_256(s1, sbuf);
    __syncthreads();
    cnt = block_sum_256(cnt, sbuf);
    if (threadIdx.x == 0) {
        pb[80 + tensor * BPT + blk]  = s1;
        pb[160 + tensor * BPT + blk] = cnt;
    }
}

// ---------------------------------------------------------------------------
// conv12: per image, conv1 (fp32 VALU, +-1 weights) -> tanh(a1*.+b1) -> pool
// into LDS bf16 NHWC tile, then conv2 MFMA -> h-pool in reg -> hbuf ->
// v-pool + tanh(a2*.+b2) -> p2b.
template<int TBASE, int TCNT>
__device__ __forceinline__ void conv2_phase(
        const ushort* __restrict__ w2b, const ushort* sxt,
        int n0, int mt0, int lane, f32x4 acc[4][2]) {
    const int col = lane & 15, quad = lane >> 4;
    bf16x8 bfr[TCNT][2];
    #pragma unroll
    for (int i = 0; i < TCNT; ++i) {
        const int tap = TBASE + i;
        #pragma unroll
        for (int np = 0; np < 2; ++np) {
            const int oc = n0 + np * 16 + col;
            bfr[i][np] = *(const bf16x8*)(w2b + (oc * 25 + tap) * 32 + quad * 8);
        }
    }
    #pragma unroll
    for (int mi = 0; mi < 4; ++mi) {
        int m = (mt0 + mi) * 16 + col;
        m = m < 100 ? m : 99;                     // clamp padding rows
        const int oh = m / 10, ow = m - oh * 10;
        const ushort* abase = sxt + (oh * 14 + ow) * 40 + quad * 8;
        #pragma unroll
        for (int i = 0; i < TCNT; ++i) {
            const int tap = TBASE + i;
            const int kh = tap / 5, kw = tap - kh * 5;
            bf16x8 af = *(const bf16x8*)(abase + (kh * 14 + kw) * 40);
            acc[mi][0] = __builtin_amdgcn_mfma_f32_16x16x32_bf16(af, bfr[i][0], acc[mi][0], 0, 0, 0);
            acc[mi][1] = __builtin_amdgcn_mfma_f32_16x16x32_bf16(af, bfr[i][1], acc[mi][1], 0, 0, 0);
        }
    }
}

__global__ __launch_bounds__(256)
void conv12_kernel(const float* __restrict__ x, const float* __restrict__ q1t,
                   const float* __restrict__ b1, const ushort* __restrict__ w2b,
                   const float* __restrict__ b2, const float* __restrict__ pb,
                   ushort* __restrict__ p2b) {
    __shared__ __align__(16) ushort sxt[196 * 40];  // pooled1 tile, NHWC, stride 40
    __shared__ __align__(16) float hbuf[64 * 50];   // h-pooled conv2 out [oc][h]
    __shared__ float salpha[2];
    // sx (1024 f32) and sw (800 f32) overlay hbuf: dead before hbuf is written
    float* sx = hbuf;
    float* sw = hbuf + 1024;

    const int n = blockIdx.x;
    const int t = threadIdx.x;
    {
        const float4* src = (const float4*)(x + (size_t)n * 1024);
        if (t < 256) ((float4*)sx)[t] = src[t];
        if (t < 200) ((float4*)sw)[t] = ((const float4*)q1t)[t];
        if (t == 0) salpha[0] = alpha_of(pb, 0);
        if (t == 1) salpha[1] = alpha_of(pb, 1);
    }
    __syncthreads();

    // ---- conv1 -> sxt --------------------------------------------------
    const float a1 = salpha[0];
    const int ocg  = t >> 5;
    const int pos0 = t & 31;
    float bias[4];
    #pragma unroll
    for (int o = 0; o < 4; ++o) bias[o] = b1[ocg * 4 + o];

    for (int pos = pos0; pos < 196; pos += 32) {
        const int ph = pos / 14, pw = pos - ph * 14;
        const int r0 = 2 * ph, c0 = 2 * pw;
        float acc[4][4] = {};
        const float4* wp = (const float4*)sw + ocg;
        #pragma unroll
        for (int kh = 0; kh < 5; ++kh) {
            const float* xr = sx + (r0 + kh) * 32 + c0;   // c0 even -> 8B aligned
            float2 pa0 = *(const float2*)&xr[0];
            float2 pa1 = *(const float2*)&xr[2];
            float2 pa2 = *(const float2*)&xr[4];
            float2 pb0 = *(const float2*)&xr[32];
            float2 pb1 = *(const float2*)&xr[34];
            float2 pb2 = *(const float2*)&xr[36];
            const float xa[6] = {pa0.x, pa0.y, pa1.x, pa1.y, pa2.x, pa2.y};
            const float xb[6] = {pb0.x, pb0.y, pb1.x, pb1.y, pb2.x, pb2.y};
            #pragma unroll
            for (int kw = 0; kw < 5; ++kw) {
                const float4 w4 = *wp; wp += 8;
                const float x00 = xa[kw], x01 = xa[kw + 1];
                const float x10 = xb[kw], x11 = xb[kw + 1];
                acc[0][0] = fmaf(w4.x, x00, acc[0][0]);
                acc[0][1] = fmaf(w4.x, x01, acc[0][1]);
                acc[0][2] = fmaf(w4.x, x10, acc[0][2]);
                acc[0][3] = fmaf(w4.x, x11, acc[0][3]);
                acc[1][0] = fmaf(w4.y, x00, acc[1][0]);
                acc[1][1] = fmaf(w4.y, x01, acc[1][1]);
                acc[1][2] = fmaf(w4.y, x10, acc[1][2]);
                acc[1][3] = fmaf(w4.y, x11, acc[1][3]);
                acc[2][0] = fmaf(w4.z, x00, acc[2][0]);
                acc[2][1] = fmaf(w4.z, x01, acc[2][1]);
                acc[2][2] = fmaf(w4.z, x10, acc[2][2]);
                acc[2][3] = fmaf(w4.z, x11, acc[2][3]);
                acc[3][0] = fmaf(w4.w, x00, acc[3][0]);
                acc[3][1] = fmaf(w4.w, x01, acc[3][1]);
                acc[3][2] = fmaf(w4.w, x10, acc[3][2]);
                acc[3][3] = fmaf(w4.w, x11, acc[3][3]);
            }
        }
        ushort4 qv;
        {
            float m0 = fmaxf(fmaxf(acc[0][0], acc[0][1]), fmaxf(acc[0][2], acc[0][3]));
            float m1 = fmaxf(fmaxf(acc[1][0], acc[1][1]), fmaxf(acc[1][2], acc[1][3]));
            float m2 = fmaxf(fmaxf(acc[2][0], acc[2][1]), fmaxf(acc[2][2], acc[2][3]));
            float m3 = fmaxf(fmaxf(acc[3][0], acc[3][1]), fmaxf(acc[3][2], acc[3][3]));
            qv.x = f2bf(tanh_fast(fmaf(a1, m0, bias[0])));
            qv.y = f2bf(tanh_fast(fmaf(a1, m1, bias[1])));
            qv.z = f2bf(tanh_fast(fmaf(a1, m2, bias[2])));
            qv.w = f2bf(tanh_fast(fmaf(a1, m3, bias[3])));
        }
        *(ushort4*)(&sxt[pos * 40 + ocg * 4]) = qv;
    }
    __syncthreads();   // conv1 done; sx/sw dead; sxt ready

    // ---- conv2 MFMA ----------------------------------------------------
    const int wave = t >> 6, lane = t & 63;
    const int n0  = (wave & 1) * 32;
    const int mt0 = (wave >> 1) * 4;
    f32x4 acc2[4][2] = {};
    conv2_phase<0, 13>(w2b, sxt, n0, mt0, lane, acc2);
    conv2_phase<13, 12>(w2b, sxt, n0, mt0, lane, acc2);

    {   // horizontal pool in-register, write hbuf[oc][50].
        // Lane owns pixels mrow..mrow+3 (consecutive; width 10 even ->
        // (2k,2k+1) are always horizontal pool pairs). mrow%4==0 -> h even
        // -> float2 aligned.
        const int col = lane & 15, quad = lane >> 4;
        #pragma unroll
        for (int mi = 0; mi < 4; ++mi) {
            const int mrow = (mt0 + mi) * 16 + quad * 4;
            if (mrow < 100) {
                #pragma unroll
                for (int np = 0; np < 2; ++np) {
                    const int oc = n0 + np * 16 + col;
                    float2 hm;
                    hm.x = fmaxf(acc2[mi][np][0], acc2[mi][np][1]);
                    hm.y = fmaxf(acc2[mi][np][2], acc2[mi][np][3]);
                    *(float2*)(&hbuf[oc * 50 + (mrow >> 1)]) = hm;
                }
            }
        }
    }
    __syncthreads();

    // vertical pool + alpha/bias + tanh -> p2b bf16 [n][1600] (k = oc*25+pix)
    const float a2 = salpha[1];
    for (int idx = t; idx < 1600; idx += 256) {
        const int oc = idx / 25, r = idx - oc * 25;
        const int ph = r / 5, pw = r - ph * 5;
        const float* hb = &hbuf[oc * 50 + ph * 10 + pw];
        float m = fmaxf(hb[0], hb[5]);
        p2b[(size_t)n * 1600 + idx] = f2bf(tanh_fast(fmaf(a2, m, b2[oc])));
    }
}

// ---------------------------------------------------------------------------
// conv3 as MFMA GEMM: h3[1024][120] = tanh(a3*(P2 x W3^T) + b3)
// Grid 256 = 64 m-tiles x 4 oc-pairs. Waves split K 13/13/12/12; LDS reduce.
template<int STEPS>
__device__ __forceinline__ void conv3_chunk(const ushort* Abase, const ushort* B0,
                                            const ushort* B1, f32x4& acc0, f32x4& acc1) {
    #pragma unroll
    for (int s = 0; s < STEPS; ++s) {
        bf16x8 af = *(const bf16x8*)(Abase + s * 32);
        bf16x8 b0 = *(const bf16x8*)(B0 + s * 32);
        bf16x8 b1 = *(const bf16x8*)(B1 + s * 32);
        acc0 = __builtin_amdgcn_mfma_f32_16x16x32_bf16(af, b0, acc0, 0, 0, 0);
        acc1 = __builtin_amdgcn_mfma_f32_16x16x32_bf16(af, b1, acc1, 0, 0, 0);
    }
}

__global__ __launch_bounds__(256)
void conv3_mfma(const ushort* __restrict__ p2b, const ushort* __restrict__ w3b,
                const float* __restrict__ b3, const float* __restrict__ pb,
                float* __restrict__ h3) {
    __shared__ float red[4][64][8];   // [wave][lane][np*4+reg]
    __shared__ float salpha;
    const int t = threadIdx.x;
    const int wave = t >> 6, lane = t & 63;
    const int mt = blockIdx.x >> 2;       // 0..63
    const int npair = blockIdx.x & 3;     // 0..3
    const int col = lane & 15, quad = lane >> 4;
    const int kstart = (wave < 2) ? wave * 13 : 26 + (wave - 2) * 12;  // 0,13,26,38

    if (t == 0) salpha = alpha_of(pb, 2);

    const ushort* Abase = p2b + (size_t)(mt * 16 + col) * 1600 + kstart * 32 + quad * 8;
    const ushort* B0 = w3b + (size_t)(npair * 32 + col) * 1600 + kstart * 32 + quad * 8;
    const ushort* B1 = B0 + 16 * 1600;

    f32x4 acc0 = {}, acc1 = {};
    if (wave < 2) conv3_chunk<13>(Abase, B0, B1, acc0, acc1);
    else          conv3_chunk<12>(Abase, B0, B1, acc0, acc1);

    #pragma unroll
    for (int r = 0; r < 4; ++r) {
        red[wave][lane][r]     = acc0[r];
        red[wave][lane][4 + r] = acc1[r];
    }
    __syncthreads();

    {   // thread t: lane l = t&63, reg vh = t>>6; handles np = 0 and 1
        const float a3 = salpha;
        const int l = t & 63, vh = t >> 6;
        const int lcol = l & 15, lquad = l >> 4;
        const int img = mt * 16 + lquad * 4 + vh;
        #pragma unroll
        for (int j = 0; j < 2; ++j) {
            const int v = j * 4 + vh;
            float s = red[0][l][v] + red[1][l][v] + red[2][l][v] + red[3][l][v];
            const int oc = npair * 32 + j * 16 + lcol;
            if (oc < 120) h3[(size_t)img * 120 + oc] = tanh_fast(fmaf(a3, s, b3[oc]));
        }
    }
}

// ---------------------------------------------------------------------------
// fc1 + tanh + fc2 + softmax. Block per image; alpha folded.
__global__ __launch_bounds__(128)
void fc_kernel(const float* __restrict__ h3, const float* __restrict__ fw1t,
               const float* __restrict__ fb1, const float* __restrict__ fw2t,
               const float* __restrict__ fb2, const float* __restrict__ pb,
               float* __restrict__ out) {
    const int n = blockIdx.x;
    __shared__ float sh[120];
    __shared__ float sh4[84];
    __shared__ float sl[10];
    __shared__ float salpha[2];
    const int t = threadIdx.x;
    if (t < 120) sh[t] = h3[(size_t)n * 120 + t];
    if (t == 120) salpha[0] = alpha_of(pb, 3);
    if (t == 121) salpha[1] = alpha_of(pb, 4);
    __syncthreads();
    if (t < 84) {
        const float af1 = salpha[0];
        float a = 0.f;
        #pragma unroll 4
        for (int k = 0; k < 120; ++k) a = fmaf(fw1t[k * 84 + t], sh[k], a);
        sh4[t] = tanh_fast(fmaf(af1, a, fb1[t]));
    }
    __syncthreads();
    if (t < 10) {
        const float af2 = salpha[1];
        float a = 0.f;
        #pragma unroll 4
        for (int k = 0; k < 84; ++k) a = fmaf(fw2t[k * 10 + t], sh4[k], a);
        const float lg = fmaf(af2, a, fb2[t]);
        sl[t] = lg;
        out[(size_t)n * 10 + t] = lg;
    }
    __syncthreads();
    if (t < 10) {
        float m = -INFINITY;
        #pragma unroll
        for (int i = 0; i < 10; ++i) m = fmaxf(m, sl[i]);
        float s = 0.f;
        #pragma unroll
        for (int i = 0; i < 10; ++i) s += expf(sl[i] - m);
        out[10240 + (size_t)n * 10 + t] = expf(sl[t] - m) / s;
    }
}

// ---------------------------------------------------------------------------
extern "C" void kernel_launch(void* const* d_in, const int* in_sizes, int n_in,
                              void* d_out, int out_size, void* d_ws, size_t ws_size,
                              hipStream_t stream) {
    const float* x   = (const float*)d_in[0];
    const float* w1  = (const float*)d_in[1];
    const float* b1  = (const float*)d_in[2];
    const float* w2  = (const float*)d_in[3];
    const float* b2  = (const float*)d_in[4];
    const float* w3  = (const float*)d_in[5];
    const float* b3  = (const float*)d_in[6];
    const float* fw1 = (const float*)d_in[7];
    const float* fb1 = (const float*)d_in[8];
    const float* fw2 = (const float*)d_in[9];
    const float* fb2 = (const float*)d_in[10];

    float* ws = (float*)d_ws;
    float*  pb   = ws + OFF_PB;
    float*  q1t  = ws + OFF_Q1T;
    ushort* w2b  = (ushort*)(ws + OFF_W2B);
    ushort* w3b  = (ushort*)(ws + OFF_W3B);
    float*  fw1t = ws + OFF_FW1T;
    float*  fw2t = ws + OFF_FW2T;
    ushort* p2b  = (ushort*)(ws + OFF_P2B);
    float*  h3   = ws + OFF_H3;
    float*  out  = (float*)d_out;

    tern_pass1<<<5 * BPT, 256, 0, stream>>>(w1, w2, w3, fw1, fw2, pb);
    tern_pass2<<<5 * BPT, 256, 0, stream>>>(w1, w2, w3, fw1, fw2,
                                            q1t, w2b, w3b, fw1t, fw2t, pb);
    conv12_kernel<<<1024, 256, 0, stream>>>(x, q1t, b1, w2b, b2, pb, p2b);
    conv3_mfma<<<256, 256, 0, stream>>>(p2b, w3b, b3, pb, h3);
    fc_kernel<<<1024, 128, 0, stream>>>(h3, fw1t, fb1, fw2t, fb2, pb, out);
}